// Round 1
// baseline (2092.469 us; speedup 1.0000x reference)
//
#include <hip/hip_runtime.h>
#include <math.h>

#define N_NODES 50000
#define N_EDGES 500000
#define D 128
#define CAT 384

__device__ __forceinline__ float gelu_exact(float x) {
    return 0.5f * x * (1.0f + erff(x * 0.70710678118654752440f));
}

// ---------------------------------------------------------------------------
// RP[r][j] = sum_k rel_emb[r][k] * msg_W[j][256+k] + msg_b[j]
__global__ void k_relpart(const float* __restrict__ rel_emb,
                          const float* __restrict__ msg_W,
                          const float* __restrict__ msg_b,
                          float* __restrict__ RP) {
    int r = blockIdx.x;
    int j = threadIdx.x;
    const float* er = rel_emb + r * D;
    const float* wr = msg_W + j * CAT + 2 * D;
    float acc = msg_b[j];
    #pragma unroll 8
    for (int k = 0; k < D; ++k) acc += er[k] * wr[k];
    RP[r * D + j] = acc;
}

// ---------------------------------------------------------------------------
// out[n][j]     = sum_k in[n][k] * w[j][k]        (j <  128)
// out[n][128+j] = sum_k in[n][k] * w[j][128+k]    (j >= 128, row j-128)
// w is [128][384] row-major. 16 nodes per block, 256 threads.
__global__ __launch_bounds__(256) void k_proj2(const float* __restrict__ in,
                                               const float* __restrict__ w,
                                               float* __restrict__ out) {
    __shared__ float in_t[16][128];
    int t = threadIdx.x;
    int n0 = blockIdx.x * 16;
    {
        const float4* g = (const float4*)(in + (size_t)n0 * D);
        float4* l = (float4*)(&in_t[0][0]);
        l[t] = g[t];
        l[t + 256] = g[t + 256];
    }
    __syncthreads();
    int j = t;
    const float* wrow = (j < 128) ? (w + j * CAT) : (w + (j - 128) * CAT + D);
    float acc[16];
    #pragma unroll
    for (int n = 0; n < 16; ++n) acc[n] = 0.f;
    for (int kc = 0; kc < 4; ++kc) {
        float wreg[32];
        #pragma unroll
        for (int i = 0; i < 32; ++i) wreg[i] = wrow[kc * 32 + i];
        #pragma unroll
        for (int i = 0; i < 32; ++i) {
            float wv = wreg[i];
            #pragma unroll
            for (int n = 0; n < 16; ++n) acc[n] += wv * in_t[n][kc * 32 + i];
        }
    }
    #pragma unroll
    for (int n = 0; n < 16; ++n) out[(size_t)(n0 + n) * 256 + j] = acc[n];
}

// ---------------------------------------------------------------------------
// Per edge: msg = gelu(PST[src][j] + PST[tgt][128+j] + RP[lab][j]); agg[tgt] += msg
__global__ __launch_bounds__(256) void k_msg(const float* __restrict__ PST,
                                             const float* __restrict__ RP,
                                             const int* __restrict__ ei,
                                             const int* __restrict__ lab,
                                             float* __restrict__ agg) {
    int t = threadIdx.x;
    int e = blockIdx.x * 2 + (t >> 7);
    int j = t & 127;
    int s = ei[e];
    int d = ei[N_EDGES + e];
    int l = lab[e];
    float v = PST[(size_t)s * 256 + j] + PST[(size_t)d * 256 + 128 + j] + RP[l * D + j];
    v = gelu_exact(v);
    atomicAdd(&agg[(size_t)d * D + j], v);
}

// ---------------------------------------------------------------------------
// Fused GRU: gi = w_ih@agg + b_ih, gh = w_hh@nf + b_hh (both in LDS), then
// elementwise GRU -> nfu. 16 nodes/block, 256 threads.
__global__ __launch_bounds__(256) void k_gru(const float* __restrict__ agg,
                                             const float* __restrict__ nf,
                                             const float* __restrict__ w_ih,
                                             const float* __restrict__ w_hh,
                                             const float* __restrict__ b_ih,
                                             const float* __restrict__ b_hh,
                                             float* __restrict__ nfu) {
    __shared__ float agg_t[16][128];
    __shared__ float nf_t[16][128];
    __shared__ float g_t[16][768];
    int t = threadIdx.x;
    int n0 = blockIdx.x * 16;
    {
        const float4* ga = (const float4*)(agg + (size_t)n0 * D);
        const float4* gn = (const float4*)(nf + (size_t)n0 * D);
        float4* la = (float4*)(&agg_t[0][0]);
        float4* ln = (float4*)(&nf_t[0][0]);
        la[t] = ga[t]; la[t + 256] = ga[t + 256];
        ln[t] = gn[t]; ln[t + 256] = gn[t + 256];
    }
    __syncthreads();
    for (int oi = 0; oi < 3; ++oi) {
        int o = t + 256 * oi;   // 0..767; wave-uniform branch below
        const float* wrow; const float* inp; float b;
        if (o < 384) { wrow = w_ih + o * D;         inp = &agg_t[0][0]; b = b_ih[o]; }
        else         { wrow = w_hh + (o - 384) * D; inp = &nf_t[0][0];  b = b_hh[o - 384]; }
        float acc[16];
        #pragma unroll
        for (int n = 0; n < 16; ++n) acc[n] = 0.f;
        for (int kc = 0; kc < 4; ++kc) {
            float wreg[32];
            #pragma unroll
            for (int i = 0; i < 32; ++i) wreg[i] = wrow[kc * 32 + i];
            #pragma unroll
            for (int i = 0; i < 32; ++i) {
                float wv = wreg[i];
                #pragma unroll
                for (int n = 0; n < 16; ++n) acc[n] += wv * inp[n * 128 + kc * 32 + i];
            }
        }
        #pragma unroll
        for (int n = 0; n < 16; ++n) g_t[n][o] = acc[n] + b;
    }
    __syncthreads();
    #pragma unroll
    for (int ii = 0; ii < 8; ++ii) {
        int idx = t + 256 * ii;           // 0..2047
        int n = idx >> 7, j = idx & 127;
        float ir = g_t[n][j],       iz = g_t[n][128 + j], inn = g_t[n][256 + j];
        float hr = g_t[n][384 + j], hz = g_t[n][512 + j], hn  = g_t[n][640 + j];
        float r = 1.f / (1.f + expf(-(ir + hr)));
        float z = 1.f / (1.f + expf(-(iz + hz)));
        float nn = tanhf(inn + r * hn);
        float h = nf_t[n][j];
        nfu[(size_t)(n0 + n) * D + j] = (1.f - z) * nn + z * h;
    }
}

// ---------------------------------------------------------------------------
// Per-edge classifier: epart = ef@V3T (V3 = cls_W1 cols 256:384), then
// hc = gelu(QST[src][j] + QST[tgt][128+j] + epart + b1), out = hc@W2T + b2.
// 32 edges per block, 256 threads.
__global__ __launch_bounds__(256) void k_cls(const float* __restrict__ ef,
                                             const float* __restrict__ QST,
                                             const float* __restrict__ W1,
                                             const float* __restrict__ b1,
                                             const float* __restrict__ W2,
                                             const float* __restrict__ b2,
                                             const int* __restrict__ ei,
                                             float* __restrict__ out) {
    __shared__ float ef_t[32][128];
    __shared__ float hc_t[32][132];
    __shared__ float w2_t[16][132];
    __shared__ int sidx[32], tidx[32];
    int t = threadIdx.x;
    int e0 = blockIdx.x * 32;
    {
        const float4* g = (const float4*)(ef + (size_t)e0 * D);
        float4* l = (float4*)(&ef_t[0][0]);
        #pragma unroll
        for (int i = 0; i < 4; ++i) l[t + 256 * i] = g[t + 256 * i];
    }
    {   // W2 (16x128) into padded LDS, scalar (pad breaks float4)
        #pragma unroll
        for (int i = 0; i < 8; ++i) {
            int idx = t + 256 * i;        // 0..2047
            int r = idx >> 7, c = idx & 127;
            w2_t[r][c] = W2[idx];
        }
    }
    if (t < 32) sidx[t] = ei[e0 + t];
    else if (t < 64) tidx[t - 32] = ei[N_EDGES + e0 + (t - 32)];
    __syncthreads();

    int j = t & 127;
    int eg = t >> 7;  // which 16-edge half this thread covers
    const float* wrow = W1 + j * CAT + 2 * D;
    float acc[16];
    #pragma unroll
    for (int n = 0; n < 16; ++n) acc[n] = 0.f;
    for (int kc = 0; kc < 4; ++kc) {
        float wreg[32];
        #pragma unroll
        for (int i = 0; i < 32; ++i) wreg[i] = wrow[kc * 32 + i];
        #pragma unroll
        for (int i = 0; i < 32; ++i) {
            float wv = wreg[i];
            #pragma unroll
            for (int n = 0; n < 16; ++n) acc[n] += wv * ef_t[eg * 16 + n][kc * 32 + i];
        }
    }
    float bj = b1[j];
    #pragma unroll
    for (int n = 0; n < 16; ++n) {
        int el = eg * 16 + n;
        float v = acc[n] + QST[(size_t)sidx[el] * 256 + j]
                         + QST[(size_t)tidx[el] * 256 + 128 + j] + bj;
        hc_t[el][j] = gelu_exact(v);
    }
    __syncthreads();

    #pragma unroll
    for (int ii = 0; ii < 2; ++ii) {
        int idx = t + 256 * ii;           // 0..511
        int el = idx >> 4, c = idx & 15;
        const float* w2r = &w2_t[c][0];
        float a = b2[c];
        #pragma unroll 16
        for (int k = 0; k < 128; ++k) a += hc_t[el][k] * w2r[k];
        out[(size_t)(e0 + el) * 16 + c] = a;
    }
}

// ---------------------------------------------------------------------------
extern "C" void kernel_launch(void* const* d_in, const int* in_sizes, int n_in,
                              void* d_out, int out_size, void* d_ws, size_t ws_size,
                              hipStream_t stream) {
    const float* nf   = (const float*)d_in[0];
    const float* ef   = (const float*)d_in[1];
    const int*   ei   = (const int*)d_in[2];
    const int*   lab  = (const int*)d_in[3];
    const float* rel  = (const float*)d_in[4];
    const float* msgW = (const float*)d_in[5];
    const float* msgb = (const float*)d_in[6];
    const float* wih  = (const float*)d_in[7];
    const float* whh  = (const float*)d_in[8];
    const float* bih  = (const float*)d_in[9];
    const float* bhh  = (const float*)d_in[10];
    const float* W1   = (const float*)d_in[11];
    const float* b1   = (const float*)d_in[12];
    const float* W2   = (const float*)d_in[13];
    const float* b2   = (const float*)d_in[14];
    float* out = (float*)d_out;

    char* ws = (char*)d_ws;
    float* RP  = (float*)(ws);                                    // 32 KB
    float* PST = (float*)(ws + 32768);                            // 51.2 MB
    float* AGG = (float*)(ws + 32768 + 51200000);                 // 25.6 MB
    float* NFU = (float*)(ws + 32768 + 51200000 + 25600000);      // 25.6 MB
    float* QST = PST;  // PST dead after k_msg; reuse for classifier proj

    k_relpart<<<64, 128, 0, stream>>>(rel, msgW, msgb, RP);
    k_proj2<<<N_NODES / 16, 256, 0, stream>>>(nf, msgW, PST);
    hipMemsetAsync(AGG, 0, (size_t)N_NODES * D * sizeof(float), stream);
    k_msg<<<N_EDGES / 2, 256, 0, stream>>>(PST, RP, ei, lab, AGG);
    k_gru<<<N_NODES / 16, 256, 0, stream>>>(AGG, nf, wih, whh, bih, bhh, NFU);
    k_proj2<<<N_NODES / 16, 256, 0, stream>>>(NFU, W1, QST);
    k_cls<<<N_EDGES / 32, 256, 0, stream>>>(ef, QST, W1, b1, W2, b2, ei, out);
}

// Round 2
// 1149.939 us; speedup vs baseline: 1.8196x; 1.8196x over previous
//
#include <hip/hip_runtime.h>
#include <math.h>

#define N_NODES 50000
#define N_EDGES 500000
#define D 128
#define CAT 384

typedef __bf16 v8bf __attribute__((ext_vector_type(8)));
typedef float v4f __attribute__((ext_vector_type(4)));

__device__ __forceinline__ float gelu_exact(float x) {
    return 0.5f * x * (1.0f + erff(x * 0.70710678118654752440f));
}

__device__ __forceinline__ v8bf cvt8(const float* __restrict__ p) {
    float4 f0 = *(const float4*)p;
    float4 f1 = *(const float4*)(p + 4);
    v8bf r;
    r[0] = (__bf16)f0.x; r[1] = (__bf16)f0.y; r[2] = (__bf16)f0.z; r[3] = (__bf16)f0.w;
    r[4] = (__bf16)f1.x; r[5] = (__bf16)f1.y; r[6] = (__bf16)f1.z; r[7] = (__bf16)f1.w;
    return r;
}

// ---------------------------------------------------------------------------
// RP[r][j] = sum_k rel_emb[r][k] * msg_W[j][256+k] + msg_b[j]
__global__ void k_relpart(const float* __restrict__ rel_emb,
                          const float* __restrict__ msg_W,
                          const float* __restrict__ msg_b,
                          float* __restrict__ RP) {
    int r = blockIdx.x;
    int j = threadIdx.x;
    const float* er = rel_emb + r * D;
    const float* wr = msg_W + j * CAT + 2 * D;
    float acc = msg_b[j];
    #pragma unroll 8
    for (int k = 0; k < D; ++k) acc += er[k] * wr[k];
    RP[r * D + j] = acc;
}

// ---------------------------------------------------------------------------
// out[n][j]     = sum_k in[n][k] * w[j][k]        (j <  128)
// out[n][128+j] = sum_k in[n][k] * w[j][128+k]    (j >= 128, row j-128)
__global__ __launch_bounds__(256) void k_proj2(const float* __restrict__ in,
                                               const float* __restrict__ w,
                                               float* __restrict__ out) {
    __shared__ float in_t[16][128];
    int t = threadIdx.x;
    int n0 = blockIdx.x * 16;
    {
        const float4* g = (const float4*)(in + (size_t)n0 * D);
        float4* l = (float4*)(&in_t[0][0]);
        l[t] = g[t];
        l[t + 256] = g[t + 256];
    }
    __syncthreads();
    int j = t;
    const float* wrow = (j < 128) ? (w + j * CAT) : (w + (j - 128) * CAT + D);
    float acc[16];
    #pragma unroll
    for (int n = 0; n < 16; ++n) acc[n] = 0.f;
    for (int kc = 0; kc < 4; ++kc) {
        float wreg[32];
        #pragma unroll
        for (int i = 0; i < 32; ++i) wreg[i] = wrow[kc * 32 + i];
        #pragma unroll
        for (int i = 0; i < 32; ++i) {
            float wv = wreg[i];
            #pragma unroll
            for (int n = 0; n < 16; ++n) acc[n] += wv * in_t[n][kc * 32 + i];
        }
    }
    #pragma unroll
    for (int n = 0; n < 16; ++n) out[(size_t)(n0 + n) * 256 + j] = acc[n];
}

// ---------------------------------------------------------------------------
// Per edge: msg = gelu(PST[src][j] + PST[tgt][128+j] + RP[lab][j]); agg[tgt] += msg
__global__ __launch_bounds__(256) void k_msg(const float* __restrict__ PST,
                                             const float* __restrict__ RP,
                                             const int* __restrict__ ei,
                                             const int* __restrict__ lab,
                                             float* __restrict__ agg) {
    int t = threadIdx.x;
    int e = blockIdx.x * 2 + (t >> 7);
    int j = t & 127;
    int s = ei[e];
    int d = ei[N_EDGES + e];
    int l = lab[e];
    float v = PST[(size_t)s * 256 + j] + PST[(size_t)d * 256 + 128 + j] + RP[l * D + j];
    v = gelu_exact(v);
    atomicAdd(&agg[(size_t)d * D + j], v);
}

// ---------------------------------------------------------------------------
// Fused GRU
__global__ __launch_bounds__(256) void k_gru(const float* __restrict__ agg,
                                             const float* __restrict__ nf,
                                             const float* __restrict__ w_ih,
                                             const float* __restrict__ w_hh,
                                             const float* __restrict__ b_ih,
                                             const float* __restrict__ b_hh,
                                             float* __restrict__ nfu) {
    __shared__ float agg_t[16][128];
    __shared__ float nf_t[16][128];
    __shared__ float g_t[16][768];
    int t = threadIdx.x;
    int n0 = blockIdx.x * 16;
    {
        const float4* ga = (const float4*)(agg + (size_t)n0 * D);
        const float4* gn = (const float4*)(nf + (size_t)n0 * D);
        float4* la = (float4*)(&agg_t[0][0]);
        float4* ln = (float4*)(&nf_t[0][0]);
        la[t] = ga[t]; la[t + 256] = ga[t + 256];
        ln[t] = gn[t]; ln[t + 256] = gn[t + 256];
    }
    __syncthreads();
    for (int oi = 0; oi < 3; ++oi) {
        int o = t + 256 * oi;
        const float* wrow; const float* inp; float b;
        if (o < 384) { wrow = w_ih + o * D;         inp = &agg_t[0][0]; b = b_ih[o]; }
        else         { wrow = w_hh + (o - 384) * D; inp = &nf_t[0][0];  b = b_hh[o - 384]; }
        float acc[16];
        #pragma unroll
        for (int n = 0; n < 16; ++n) acc[n] = 0.f;
        for (int kc = 0; kc < 4; ++kc) {
            float wreg[32];
            #pragma unroll
            for (int i = 0; i < 32; ++i) wreg[i] = wrow[kc * 32 + i];
            #pragma unroll
            for (int i = 0; i < 32; ++i) {
                float wv = wreg[i];
                #pragma unroll
                for (int n = 0; n < 16; ++n) acc[n] += wv * inp[n * 128 + kc * 32 + i];
            }
        }
        #pragma unroll
        for (int n = 0; n < 16; ++n) g_t[n][o] = acc[n] + b;
    }
    __syncthreads();
    #pragma unroll
    for (int ii = 0; ii < 8; ++ii) {
        int idx = t + 256 * ii;
        int n = idx >> 7, j = idx & 127;
        float ir = g_t[n][j],       iz = g_t[n][128 + j], inn = g_t[n][256 + j];
        float hr = g_t[n][384 + j], hz = g_t[n][512 + j], hn  = g_t[n][640 + j];
        float r = 1.f / (1.f + expf(-(ir + hr)));
        float z = 1.f / (1.f + expf(-(iz + hz)));
        float nn = tanhf(inn + r * hn);
        float h = nf_t[n][j];
        nfu[(size_t)(n0 + n) * D + j] = (1.f - z) * nn + z * h;
    }
}

// ---------------------------------------------------------------------------
// MFMA classifier: 64 edges/block, 4 waves, 16 edges/wave.
// GEMM1: epart[e][j] = ef[e][:] @ W1[j][256:384]   (bf16 MFMA, fp32 acc)
// epilogue: hc = gelu(epart + QST[src][j] + QST[tgt][128+j] + b1[j]) -> bf16 LDS
// GEMM2: out[e][c] = hc[e][:] @ W2[c][:] + b2[c]   (bf16 MFMA)
// mfma_f32_16x16x32_bf16: A row=lane&15, k=(lane>>4)*8+i (8 consecutive);
// B col=lane&15, same k; C col=lane&15, row=(lane>>4)*4+reg.
__global__ __launch_bounds__(256) void k_cls_mfma(const float* __restrict__ ef,
                                                  const float* __restrict__ QST,
                                                  const float* __restrict__ W1,
                                                  const float* __restrict__ b1,
                                                  const float* __restrict__ W2,
                                                  const float* __restrict__ b2,
                                                  const int* __restrict__ ei,
                                                  float* __restrict__ out) {
    __shared__ __align__(16) __bf16 hc_s[64][128];   // 16 KB, XOR-swizzled cols
    __shared__ __align__(16) __bf16 w2_s[16][128];   // 4 KB, XOR-swizzled cols
    __shared__ int sidx_s[64], tidx_s[64];
    int t = threadIdx.x;
    int lane = t & 63, w = t >> 6;
    int g = lane >> 4, c = lane & 15;
    int e0 = blockIdx.x * 64;
    int e_base = e0 + w * 16;

    // stage W2 as bf16, swizzle: col ^= (row&7)<<3 (16B granules)
    for (int i = t; i < 16 * 128; i += 256) {
        int r = i >> 7, cc = i & 127;
        w2_s[r][cc ^ ((r & 7) << 3)] = (__bf16)W2[i];
    }
    if (t < 64)       { int e = min(e0 + t, N_EDGES - 1);       sidx_s[t] = ei[e]; }
    else if (t < 128) { int e = min(e0 + t - 64, N_EDGES - 1);  tidx_s[t - 64] = ei[N_EDGES + e]; }

    // A fragments: ef row (e_base + c), k = g*8 + 32*kc .. +8
    int er = min(e_base + c, N_EDGES - 1);
    const float* efr = ef + (size_t)er * D + g * 8;
    v8bf afrag[4];
    #pragma unroll
    for (int kc = 0; kc < 4; ++kc) afrag[kc] = cvt8(efr + kc * 32);

    v4f acc[8];
    #pragma unroll
    for (int jt = 0; jt < 8; ++jt) acc[jt] = (v4f){0.f, 0.f, 0.f, 0.f};

    // GEMM1: B streamed from W1 (L2-hot): B[k][j] = W1[j][256+k]
    #pragma unroll 2
    for (int jt = 0; jt < 8; ++jt) {
        const float* wr = W1 + (size_t)(c + 16 * jt) * CAT + 256 + g * 8;
        v4f a4 = acc[jt];
        #pragma unroll
        for (int kc = 0; kc < 4; ++kc) {
            v8bf bb = cvt8(wr + kc * 32);
            a4 = __builtin_amdgcn_mfma_f32_16x16x32_bf16(afrag[kc], bb, a4, 0, 0, 0);
        }
        acc[jt] = a4;
    }

    __syncthreads();   // w2_s + sidx/tidx staged

    // epilogue: gather + gelu -> bf16 hc_s (swizzled)
    #pragma unroll
    for (int r = 0; r < 4; ++r) {
        int el = w * 16 + g * 4 + r;
        const float* qs = QST + (size_t)sidx_s[el] * 256;
        const float* qt = QST + (size_t)tidx_s[el] * 256 + 128;
        int sw = (el & 7) << 3;
        #pragma unroll
        for (int jt = 0; jt < 8; ++jt) {
            int j = c + 16 * jt;
            float v = acc[jt][r] + qs[j] + qt[j] + b1[j];
            hc_s[el][j ^ sw] = (__bf16)gelu_exact(v);
        }
    }
    __syncthreads();

    // GEMM2: A = hc (row = w*16+c), B[k=j][col=c] = W2[c][j]
    v4f acc2 = (v4f){0.f, 0.f, 0.f, 0.f};
    int row = w * 16 + c;
    int sw2 = (c & 7) << 3;   // row&7 == c&7 for both hc row and w2 row
    #pragma unroll
    for (int kc = 0; kc < 4; ++kc) {
        v8bf aa = *(const v8bf*)&hc_s[row][(g * 8 + 32 * kc) ^ sw2];
        v8bf bb = *(const v8bf*)&w2_s[c][(g * 8 + 32 * kc) ^ sw2];
        acc2 = __builtin_amdgcn_mfma_f32_16x16x32_bf16(aa, bb, acc2, 0, 0, 0);
    }
    float b2c = b2[c];
    #pragma unroll
    for (int r = 0; r < 4; ++r) {
        int e = e_base + g * 4 + r;
        if (e < N_EDGES) out[(size_t)e * 16 + c] = acc2[r] + b2c;
    }
}

// ---------------------------------------------------------------------------
extern "C" void kernel_launch(void* const* d_in, const int* in_sizes, int n_in,
                              void* d_out, int out_size, void* d_ws, size_t ws_size,
                              hipStream_t stream) {
    const float* nf   = (const float*)d_in[0];
    const float* ef   = (const float*)d_in[1];
    const int*   ei   = (const int*)d_in[2];
    const int*   lab  = (const int*)d_in[3];
    const float* rel  = (const float*)d_in[4];
    const float* msgW = (const float*)d_in[5];
    const float* msgb = (const float*)d_in[6];
    const float* wih  = (const float*)d_in[7];
    const float* whh  = (const float*)d_in[8];
    const float* bih  = (const float*)d_in[9];
    const float* bhh  = (const float*)d_in[10];
    const float* W1   = (const float*)d_in[11];
    const float* b1   = (const float*)d_in[12];
    const float* W2   = (const float*)d_in[13];
    const float* b2   = (const float*)d_in[14];
    float* out = (float*)d_out;

    char* ws = (char*)d_ws;
    float* RP  = (float*)(ws);                                    // 32 KB
    float* PST = (float*)(ws + 32768);                            // 51.2 MB
    float* AGG = (float*)(ws + 32768 + 51200000);                 // 25.6 MB
    float* NFU = (float*)(ws + 32768 + 51200000 + 25600000);      // 25.6 MB
    float* QST = PST;  // PST dead after k_msg; reuse for classifier proj

    k_relpart<<<64, 128, 0, stream>>>(rel, msgW, msgb, RP);
    k_proj2<<<N_NODES / 16, 256, 0, stream>>>(nf, msgW, PST);
    hipMemsetAsync(AGG, 0, (size_t)N_NODES * D * sizeof(float), stream);
    k_msg<<<N_EDGES / 2, 256, 0, stream>>>(PST, RP, ei, lab, AGG);
    k_gru<<<N_NODES / 16, 256, 0, stream>>>(AGG, nf, wih, whh, bih, bhh, NFU);
    k_proj2<<<N_NODES / 16, 256, 0, stream>>>(NFU, W1, QST);
    k_cls_mfma<<<(N_EDGES + 63) / 64, 256, 0, stream>>>(ef, QST, W1, b1, W2, b2, ei, out);
}

// Round 3
// 865.607 us; speedup vs baseline: 2.4173x; 1.3285x over previous
//
#include <hip/hip_runtime.h>
#include <math.h>

#define N_NODES 50000
#define N_EDGES 500000
#define D 128
#define CAT 384

typedef __bf16 v8bf __attribute__((ext_vector_type(8)));
typedef float v4f __attribute__((ext_vector_type(4)));

__device__ __forceinline__ float gelu_exact(float x) {
    return 0.5f * x * (1.0f + erff(x * 0.70710678118654752440f));
}

__device__ __forceinline__ v8bf cvt8(const float* __restrict__ p) {
    float4 f0 = *(const float4*)p;
    float4 f1 = *(const float4*)(p + 4);
    v8bf r;
    r[0] = (__bf16)f0.x; r[1] = (__bf16)f0.y; r[2] = (__bf16)f0.z; r[3] = (__bf16)f0.w;
    r[4] = (__bf16)f1.x; r[5] = (__bf16)f1.y; r[6] = (__bf16)f1.z; r[7] = (__bf16)f1.w;
    return r;
}

// ---------------------------------------------------------------------------
// RP[r][j] = sum_k rel_emb[r][k] * msg_W[j][256+k] + msg_b[j]
__global__ void k_relpart(const float* __restrict__ rel_emb,
                          const float* __restrict__ msg_W,
                          const float* __restrict__ msg_b,
                          float* __restrict__ RP) {
    int r = blockIdx.x;
    int j = threadIdx.x;
    const float* er = rel_emb + r * D;
    const float* wr = msg_W + j * CAT + 2 * D;
    float acc = msg_b[j];
    #pragma unroll 8
    for (int k = 0; k < D; ++k) acc += er[k] * wr[k];
    RP[r * D + j] = acc;
}

// ---------------------------------------------------------------------------
// MFMA node projection: out[n][j] (j in 0..255)
//   j < 128 : sum_k in[n][k] * w[j][k]
//   j >= 128: sum_k in[n][k] * w[j-128][128+k]
// 64 nodes/block, 4 waves x 16 nodes. A = in rows (bf16 frags), B streamed
// from L2-hot w. mfma_f32_16x16x32_bf16: A row=lane&15, k=(lane>>4)*8+i;
// C col=lane&15, row=(lane>>4)*4+reg.
__global__ __launch_bounds__(256) void k_proj2_mfma(const float* __restrict__ in,
                                                    const float* __restrict__ w,
                                                    float* __restrict__ out) {
    int t = threadIdx.x;
    int lane = t & 63, wid = t >> 6;
    int g = lane >> 4, c = lane & 15;
    int nbase = blockIdx.x * 64 + wid * 16;

    int nrow = min(nbase + c, N_NODES - 1);
    const float* ir = in + (size_t)nrow * D + g * 8;
    v8bf afrag[4];
    #pragma unroll
    for (int kc = 0; kc < 4; ++kc) afrag[kc] = cvt8(ir + kc * 32);

    #pragma unroll 2
    for (int jt = 0; jt < 16; ++jt) {
        int j = jt * 16 + c;
        const float* wr = (j < 128) ? (w + (size_t)j * CAT + g * 8)
                                    : (w + (size_t)(j - 128) * CAT + D + g * 8);
        v4f acc = (v4f){0.f, 0.f, 0.f, 0.f};
        #pragma unroll
        for (int kc = 0; kc < 4; ++kc)
            acc = __builtin_amdgcn_mfma_f32_16x16x32_bf16(afrag[kc], cvt8(wr + kc * 32), acc, 0, 0, 0);
        #pragma unroll
        for (int r = 0; r < 4; ++r) {
            int node = nbase + g * 4 + r;
            if (node < N_NODES) out[(size_t)node * 256 + j] = acc[r];
        }
    }
}

// ---------------------------------------------------------------------------
// Per edge: msg = gelu(PST[src][j] + PST[tgt][128+j] + RP[lab][j]); agg[tgt] += msg
__global__ __launch_bounds__(256) void k_msg(const float* __restrict__ PST,
                                             const float* __restrict__ RP,
                                             const int* __restrict__ ei,
                                             const int* __restrict__ lab,
                                             float* __restrict__ agg) {
    int t = threadIdx.x;
    int e = blockIdx.x * 2 + (t >> 7);
    int j = t & 127;
    int s = ei[e];
    int d = ei[N_EDGES + e];
    int l = lab[e];
    float v = PST[(size_t)s * 256 + j] + PST[(size_t)d * 256 + 128 + j] + RP[l * D + j];
    v = gelu_exact(v);
    atomicAdd(&agg[(size_t)d * D + j], v);
}

// ---------------------------------------------------------------------------
// MFMA GRU: per 16-col j-tile compute 6 gate tiles (i_r,i_z,i_n,h_r,h_z,h_n)
// via MFMA (A = agg/nf bf16 frags, B streamed from gru weights), then the
// GRU elementwise math in the C fragment. No LDS.
__global__ __launch_bounds__(256) void k_gru_mfma(const float* __restrict__ agg,
                                                  const float* __restrict__ nf,
                                                  const float* __restrict__ w_ih,
                                                  const float* __restrict__ w_hh,
                                                  const float* __restrict__ b_ih,
                                                  const float* __restrict__ b_hh,
                                                  float* __restrict__ nfu) {
    int t = threadIdx.x;
    int lane = t & 63, wid = t >> 6;
    int g = lane >> 4, c = lane & 15;
    int nbase = blockIdx.x * 64 + wid * 16;

    int nrow = min(nbase + c, N_NODES - 1);
    const float* ar = agg + (size_t)nrow * D + g * 8;
    const float* hr = nf + (size_t)nrow * D + g * 8;
    v8bf afrag[4], hfrag[4];
    #pragma unroll
    for (int kc = 0; kc < 4; ++kc) {
        afrag[kc] = cvt8(ar + kc * 32);
        hfrag[kc] = cvt8(hr + kc * 32);
    }

    for (int jt = 0; jt < 8; ++jt) {
        int j = jt * 16 + c;
        const float* wir = w_ih + (size_t)j * D + g * 8;
        const float* whr = w_hh + (size_t)j * D + g * 8;
        v4f a_ir = (v4f){0.f,0.f,0.f,0.f}, a_iz = a_ir, a_in = a_ir;
        v4f a_hr = a_ir, a_hz = a_ir, a_hn = a_ir;
        #pragma unroll
        for (int kc = 0; kc < 4; ++kc) {
            a_ir = __builtin_amdgcn_mfma_f32_16x16x32_bf16(afrag[kc], cvt8(wir + kc * 32), a_ir, 0, 0, 0);
            a_iz = __builtin_amdgcn_mfma_f32_16x16x32_bf16(afrag[kc], cvt8(wir + 128 * D + kc * 32), a_iz, 0, 0, 0);
            a_in = __builtin_amdgcn_mfma_f32_16x16x32_bf16(afrag[kc], cvt8(wir + 256 * D + kc * 32), a_in, 0, 0, 0);
            a_hr = __builtin_amdgcn_mfma_f32_16x16x32_bf16(hfrag[kc], cvt8(whr + kc * 32), a_hr, 0, 0, 0);
            a_hz = __builtin_amdgcn_mfma_f32_16x16x32_bf16(hfrag[kc], cvt8(whr + 128 * D + kc * 32), a_hz, 0, 0, 0);
            a_hn = __builtin_amdgcn_mfma_f32_16x16x32_bf16(hfrag[kc], cvt8(whr + 256 * D + kc * 32), a_hn, 0, 0, 0);
        }
        float bir = b_ih[j], biz = b_ih[128 + j], bin = b_ih[256 + j];
        float bhr = b_hh[j], bhz = b_hh[128 + j], bhn = b_hh[256 + j];
        #pragma unroll
        for (int r = 0; r < 4; ++r) {
            int node = nbase + g * 4 + r;
            if (node < N_NODES) {
                float irv = a_ir[r] + bir, hrv = a_hr[r] + bhr;
                float izv = a_iz[r] + biz, hzv = a_hz[r] + bhz;
                float inv = a_in[r] + bin, hnv = a_hn[r] + bhn;
                float rg = 1.f / (1.f + expf(-(irv + hrv)));
                float zg = 1.f / (1.f + expf(-(izv + hzv)));
                float ng = tanhf(inv + rg * hnv);
                float h = nf[(size_t)node * D + j];
                nfu[(size_t)node * D + j] = (1.f - zg) * ng + zg * h;
            }
        }
    }
}

// ---------------------------------------------------------------------------
// MFMA classifier: 64 edges/block, 4 waves, 16 edges/wave (unchanged, r1).
__global__ __launch_bounds__(256) void k_cls_mfma(const float* __restrict__ ef,
                                                  const float* __restrict__ QST,
                                                  const float* __restrict__ W1,
                                                  const float* __restrict__ b1,
                                                  const float* __restrict__ W2,
                                                  const float* __restrict__ b2,
                                                  const int* __restrict__ ei,
                                                  float* __restrict__ out) {
    __shared__ __align__(16) __bf16 hc_s[64][128];
    __shared__ __align__(16) __bf16 w2_s[16][128];
    __shared__ int sidx_s[64], tidx_s[64];
    int t = threadIdx.x;
    int lane = t & 63, w = t >> 6;
    int g = lane >> 4, c = lane & 15;
    int e0 = blockIdx.x * 64;
    int e_base = e0 + w * 16;

    for (int i = t; i < 16 * 128; i += 256) {
        int r = i >> 7, cc = i & 127;
        w2_s[r][cc ^ ((r & 7) << 3)] = (__bf16)W2[i];
    }
    if (t < 64)       { int e = min(e0 + t, N_EDGES - 1);       sidx_s[t] = ei[e]; }
    else if (t < 128) { int e = min(e0 + t - 64, N_EDGES - 1);  tidx_s[t - 64] = ei[N_EDGES + e]; }

    int er = min(e_base + c, N_EDGES - 1);
    const float* efr = ef + (size_t)er * D + g * 8;
    v8bf afrag[4];
    #pragma unroll
    for (int kc = 0; kc < 4; ++kc) afrag[kc] = cvt8(efr + kc * 32);

    v4f acc[8];
    #pragma unroll
    for (int jt = 0; jt < 8; ++jt) acc[jt] = (v4f){0.f, 0.f, 0.f, 0.f};

    #pragma unroll 2
    for (int jt = 0; jt < 8; ++jt) {
        const float* wr = W1 + (size_t)(c + 16 * jt) * CAT + 256 + g * 8;
        v4f a4 = acc[jt];
        #pragma unroll
        for (int kc = 0; kc < 4; ++kc) {
            v8bf bb = cvt8(wr + kc * 32);
            a4 = __builtin_amdgcn_mfma_f32_16x16x32_bf16(afrag[kc], bb, a4, 0, 0, 0);
        }
        acc[jt] = a4;
    }

    __syncthreads();

    #pragma unroll
    for (int r = 0; r < 4; ++r) {
        int el = w * 16 + g * 4 + r;
        const float* qs = QST + (size_t)sidx_s[el] * 256;
        const float* qt = QST + (size_t)tidx_s[el] * 256 + 128;
        int sw = (el & 7) << 3;
        #pragma unroll
        for (int jt = 0; jt < 8; ++jt) {
            int j = c + 16 * jt;
            float v = acc[jt][r] + qs[j] + qt[j] + b1[j];
            hc_s[el][j ^ sw] = (__bf16)gelu_exact(v);
        }
    }
    __syncthreads();

    v4f acc2 = (v4f){0.f, 0.f, 0.f, 0.f};
    int row = w * 16 + c;
    int sw2 = (c & 7) << 3;
    #pragma unroll
    for (int kc = 0; kc < 4; ++kc) {
        v8bf aa = *(const v8bf*)&hc_s[row][(g * 8 + 32 * kc) ^ sw2];
        v8bf bb = *(const v8bf*)&w2_s[c][(g * 8 + 32 * kc) ^ sw2];
        acc2 = __builtin_amdgcn_mfma_f32_16x16x32_bf16(aa, bb, acc2, 0, 0, 0);
    }
    float b2c = b2[c];
    #pragma unroll
    for (int r = 0; r < 4; ++r) {
        int e = e_base + g * 4 + r;
        if (e < N_EDGES) out[(size_t)e * 16 + c] = acc2[r] + b2c;
    }
}

// ---------------------------------------------------------------------------
extern "C" void kernel_launch(void* const* d_in, const int* in_sizes, int n_in,
                              void* d_out, int out_size, void* d_ws, size_t ws_size,
                              hipStream_t stream) {
    const float* nf   = (const float*)d_in[0];
    const float* ef   = (const float*)d_in[1];
    const int*   ei   = (const int*)d_in[2];
    const int*   lab  = (const int*)d_in[3];
    const float* rel  = (const float*)d_in[4];
    const float* msgW = (const float*)d_in[5];
    const float* msgb = (const float*)d_in[6];
    const float* wih  = (const float*)d_in[7];
    const float* whh  = (const float*)d_in[8];
    const float* bih  = (const float*)d_in[9];
    const float* bhh  = (const float*)d_in[10];
    const float* W1   = (const float*)d_in[11];
    const float* b1   = (const float*)d_in[12];
    const float* W2   = (const float*)d_in[13];
    const float* b2   = (const float*)d_in[14];
    float* out = (float*)d_out;

    char* ws = (char*)d_ws;
    float* RP  = (float*)(ws);                                    // 32 KB
    float* PST = (float*)(ws + 32768);                            // 51.2 MB
    float* AGG = (float*)(ws + 32768 + 51200000);                 // 25.6 MB
    float* NFU = (float*)(ws + 32768 + 51200000 + 25600000);      // 25.6 MB
    float* QST = PST;  // PST dead after k_msg; reuse for classifier proj

    int nblk = (N_NODES + 63) / 64;
    k_relpart<<<64, 128, 0, stream>>>(rel, msgW, msgb, RP);
    k_proj2_mfma<<<nblk, 256, 0, stream>>>(nf, msgW, PST);
    hipMemsetAsync(AGG, 0, (size_t)N_NODES * D * sizeof(float), stream);
    k_msg<<<N_EDGES / 2, 256, 0, stream>>>(PST, RP, ei, lab, AGG);
    k_gru_mfma<<<nblk, 256, 0, stream>>>(AGG, nf, wih, whh, bih, bhh, NFU);
    k_proj2_mfma<<<nblk, 256, 0, stream>>>(NFU, W1, QST);
    k_cls_mfma<<<(N_EDGES + 63) / 64, 256, 0, stream>>>(ef, QST, W1, b1, W2, b2, ei, out);
}